// Round 6
// baseline (13404.672 us; speedup 1.0000x reference)
//
#include <hip/hip_runtime.h>

// Problem constants
#define B_    64
#define T_    512
#define KDIM  1024
#define HID_  1024

// Fused tile sizes
#define BM 64   // t-chunk per block iteration
#define BN 64   // h-tile per block
#define BK 16   // one numpy 4x-unrolled SIMD block (4 lanes x 4 vectors)
#define PAD 4   // row = 20 floats (80 B) keeps float4 alignment, breaks pow2 stride

// f32 correctly rounded from python float math.exp(-1.0/20.0)
#define ALPHA_F 0.95122942450071400909f

// Bit-exact replication of the harness numpy f32 reference (PyPI x86-64 wheel,
// einsum optimize=False, baseline SSE,SSE2,SSE3 -> npyv vstep=4, NO FMA):
//   per output element, 4 f32 accumulator lanes, lane l sums k = l (mod 4);
//   per 16-k block: vacc = a0b0+(a1b1+(a2b2+(a3b3+vacc)))  [mul,add separate]
//     == per-lane acc += P(12+l); += P(8+l); += P(4+l); += P(l)
//   blocks ascending k; final: (acc0+acc1)+(acc2+acc3)  [SSE3 hadd tree]
//   then one f32 bias add. Scan: mem = f32(ALPHA)*mem + I_t (2 rounded ops),
//   spike = mem>=1, reset.
__global__ __launch_bounds__(256, 4) void snn_np_exact(
    const float* __restrict__ x,     // [B,T,K] f32
    const float* __restrict__ W,     // [H,K] f32
    const float* __restrict__ bias,  // [H] f32
    float* __restrict__ spikes,      // [B,T,H] f32 out
    float* __restrict__ memf)        // [B,H] f32 out
{
#pragma clang fp contract(off)       // numpy SSE2/SSE3 path has no FMA: mul+add
    __shared__ float As[BM][BK + PAD];
    __shared__ float Bs[BN][BK + PAD];
    __shared__ float Ism[BM][BN + 1];
    __shared__ float bsh[BN];

    const int tid = threadIdx.x;
    const int bb  = blockIdx.x;             // batch index
    const int h0  = blockIdx.y * BN;        // h tile origin

    const int tx = tid & 15;                // h micro-index
    const int ty = tid >> 4;                // t micro-index
    const int srow_ = tid >> 2;             // staging row (one float4 per thread)
    const int scol_ = (tid & 3) << 2;       // staging col (0,4,8,12)

    if (tid < BN) bsh[tid] = bias[h0 + tid];

    float mem = 0.0f;                       // threads 0..63 carry h = h0+tid

    for (int t0 = 0; t0 < T_; t0 += BM) {
        // p[j][i][l]: numpy's 4-lane vector accumulator per output element
        float p[4][4][4];
#pragma unroll
        for (int j = 0; j < 4; ++j)
#pragma unroll
            for (int i = 0; i < 4; ++i)
#pragma unroll
                for (int l = 0; l < 4; ++l) p[j][i][l] = 0.0f;

        for (int k0 = 0; k0 < KDIM; k0 += BK) {   // numpy blocks, ascending
            __syncthreads();   // prev slice's As/Bs readers done (+ bsh, Ism)
            // stage one float4 of A and B per thread (64x16 tile each)
            {
                const float4 av = *(const float4*)&x[((size_t)(bb * T_ + t0 + srow_)) * KDIM + k0 + scol_];
                const float4 wv = *(const float4*)&W[((size_t)(h0 + srow_)) * KDIM + k0 + scol_];
                *(float4*)&As[srow_][scol_] = av;
                *(float4*)&Bs[srow_][scol_] = wv;
            }
            __syncthreads();
            // q = 3,2,1,0: per-lane acc += a[4q+l]*b[4q+l] (mul, then add) —
            // bitwise equal to numpy's chained a0b0+(a1b1+(a2b2+(a3b3+acc)))
#pragma unroll
            for (int q = 3; q >= 0; --q) {
                float4 a4[4], b4[4];
#pragma unroll
                for (int j = 0; j < 4; ++j)
                    a4[j] = *(const float4*)&As[ty + 16 * j][4 * q];
#pragma unroll
                for (int i = 0; i < 4; ++i)
                    b4[i] = *(const float4*)&Bs[tx + 16 * i][4 * q];
#pragma unroll
                for (int j = 0; j < 4; ++j)
#pragma unroll
                    for (int i = 0; i < 4; ++i) {
                        float prod;
                        prod = a4[j].x * b4[i].x; p[j][i][0] = p[j][i][0] + prod;
                        prod = a4[j].y * b4[i].y; p[j][i][1] = p[j][i][1] + prod;
                        prod = a4[j].z * b4[i].z; p[j][i][2] = p[j][i][2] + prod;
                        prod = a4[j].w * b4[i].w; p[j][i][3] = p[j][i][3] + prod;
                    }
            }
        }

        // SSE3 hadd tree, then bias, write I chunk to LDS
#pragma unroll
        for (int j = 0; j < 4; ++j)
#pragma unroll
            for (int i = 0; i < 4; ++i) {
                const float s01 = p[j][i][0] + p[j][i][1];
                const float s23 = p[j][i][2] + p[j][i][3];
                const float s   = s01 + s23;
                Ism[ty + 16 * j][tx + 16 * i] = s + bsh[tx + 16 * i];
            }
        __syncthreads();

        // f32 LIF scan over this chunk; one thread per h.
        if (tid < BN) {
            const size_t srow = ((size_t)(bb * T_ + t0)) * HID_ + h0 + tid;
#pragma unroll 4
            for (int t = 0; t < BM; ++t) {
                const float It = Ism[t][tid];
                const float am = ALPHA_F * mem;   // rounded mul
                mem = am + It;                    // rounded add
                const bool fire = (mem >= 1.0f);
                spikes[srow + (size_t)t * HID_] = fire ? 1.0f : 0.0f;
                if (fire) mem = 0.0f;
            }
        }
        // next chunk's first in-loop barrier orders these Ism reads before
        // the next epilogue's Ism writes (As/Bs staging doesn't touch Ism).
    }

    if (tid < BN) memf[(size_t)bb * HID_ + h0 + tid] = mem;
}

extern "C" void kernel_launch(void* const* d_in, const int* in_sizes, int n_in,
                              void* d_out, int out_size, void* d_ws, size_t ws_size,
                              hipStream_t stream) {
    const float* x    = (const float*)d_in[0];   // [B,T,K] f32
    const float* W    = (const float*)d_in[1];   // [H,K] f32
    const float* bias = (const float*)d_in[2];   // [H] f32
    float* out    = (float*)d_out;
    float* spikes = out;                          // [B,T,H]
    float* memf   = out + (size_t)B_ * T_ * HID_; // [B,H]

    dim3 grid(B_, HID_ / BN);   // 64 x 16 = 1024 blocks
    snn_np_exact<<<grid, dim3(256), 0, stream>>>(x, W, bias, spikes, memf);
}

// Round 7
// 1699.892 us; speedup vs baseline: 7.8856x; 7.8856x over previous
//
#include <hip/hip_runtime.h>

// Problem constants
#define B_    64
#define T_    512
#define KDIM  1024
#define HID_  1024

// Fused tile sizes
#define BM 64   // t-chunk per block iteration
#define BN 64   // h-tile per block
#define BK 16   // one numpy 4x-unrolled SIMD block (4 lanes x 4 vectors)
#define PAD 4   // row = 20 floats (80 B) keeps float4 alignment, breaks pow2 stride

// f32 correctly rounded from python float math.exp(-1.0/20.0)
#define ALPHA_F 0.95122942450071400909f

// Bit-exact replication of the harness numpy f32 reference (PyPI x86-64 wheel,
// einsum optimize=False, baseline SSE,SSE2,SSE3 -> npyv vstep=4, NO FMA):
//   per output element, 4 f32 accumulator lanes, lane l sums k = l (mod 4);
//   per 16-k block: vacc = a0b0+(a1b1+(a2b2+(a3b3+vacc)))  [mul,add separate]
//     == per-lane acc += P(12+l); += P(8+l); += P(4+l); += P(l)
//   blocks ascending k; final: (acc0+acc1)+(acc2+acc3)  [SSE3 hadd tree]
//   then one f32 bias add. Scan: mem = f32(ALPHA)*mem + I_t (2 rounded ops),
//   spike = mem>=1, reset.
//
// R7 change vs R6 (passing, 13.4 ms): __launch_bounds__ (256,4) -> (256,2).
// The 4-waves/EU bound capped VGPRs at 128; the ~120-reg microkernel collapsed
// to VGPR_Count=64 + scratch spills (43 GB writes + 24 GB reads per dispatch,
// HBM-bound at 63% peak). (256,2) gives the allocator a 256-reg budget: no
// scratch, 2 blocks/CU, LDS/VALU-bound floor ~1.4 ms. Arithmetic untouched.
__global__ __launch_bounds__(256, 2) void snn_np_exact(
    const float* __restrict__ x,     // [B,T,K] f32
    const float* __restrict__ W,     // [H,K] f32
    const float* __restrict__ bias,  // [H] f32
    float* __restrict__ spikes,      // [B,T,H] f32 out
    float* __restrict__ memf)        // [B,H] f32 out
{
#pragma clang fp contract(off)       // numpy SSE2/SSE3 path has no FMA: mul+add
    __shared__ float As[BM][BK + PAD];
    __shared__ float Bs[BN][BK + PAD];
    __shared__ float Ism[BM][BN + 1];
    __shared__ float bsh[BN];

    const int tid = threadIdx.x;
    const int bb  = blockIdx.x;             // batch index
    const int h0  = blockIdx.y * BN;        // h tile origin

    const int tx = tid & 15;                // h micro-index
    const int ty = tid >> 4;                // t micro-index
    const int srow_ = tid >> 2;             // staging row (one float4 per thread)
    const int scol_ = (tid & 3) << 2;       // staging col (0,4,8,12)

    if (tid < BN) bsh[tid] = bias[h0 + tid];

    float mem = 0.0f;                       // threads 0..63 carry h = h0+tid

    for (int t0 = 0; t0 < T_; t0 += BM) {
        // p[j][i][l]: numpy's 4-lane vector accumulator per output element
        float p[4][4][4];
#pragma unroll
        for (int j = 0; j < 4; ++j)
#pragma unroll
            for (int i = 0; i < 4; ++i)
#pragma unroll
                for (int l = 0; l < 4; ++l) p[j][i][l] = 0.0f;

        for (int k0 = 0; k0 < KDIM; k0 += BK) {   // numpy blocks, ascending
            __syncthreads();   // prev slice's As/Bs readers done (+ bsh, Ism)
            // stage one float4 of A and B per thread (64x16 tile each)
            {
                const float4 av = *(const float4*)&x[((size_t)(bb * T_ + t0 + srow_)) * KDIM + k0 + scol_];
                const float4 wv = *(const float4*)&W[((size_t)(h0 + srow_)) * KDIM + k0 + scol_];
                *(float4*)&As[srow_][scol_] = av;
                *(float4*)&Bs[srow_][scol_] = wv;
            }
            __syncthreads();
            // q = 3,2,1,0: per-lane acc += a[4q+l]*b[4q+l] (mul, then add) —
            // bitwise equal to numpy's chained a0b0+(a1b1+(a2b2+(a3b3+acc)))
#pragma unroll
            for (int q = 3; q >= 0; --q) {
                float4 a4[4], b4[4];
#pragma unroll
                for (int j = 0; j < 4; ++j)
                    a4[j] = *(const float4*)&As[ty + 16 * j][4 * q];
#pragma unroll
                for (int i = 0; i < 4; ++i)
                    b4[i] = *(const float4*)&Bs[tx + 16 * i][4 * q];
#pragma unroll
                for (int j = 0; j < 4; ++j)
#pragma unroll
                    for (int i = 0; i < 4; ++i) {
                        float prod;
                        prod = a4[j].x * b4[i].x; p[j][i][0] = p[j][i][0] + prod;
                        prod = a4[j].y * b4[i].y; p[j][i][1] = p[j][i][1] + prod;
                        prod = a4[j].z * b4[i].z; p[j][i][2] = p[j][i][2] + prod;
                        prod = a4[j].w * b4[i].w; p[j][i][3] = p[j][i][3] + prod;
                    }
            }
        }

        // SSE3 hadd tree, then bias, write I chunk to LDS
#pragma unroll
        for (int j = 0; j < 4; ++j)
#pragma unroll
            for (int i = 0; i < 4; ++i) {
                const float s01 = p[j][i][0] + p[j][i][1];
                const float s23 = p[j][i][2] + p[j][i][3];
                const float s   = s01 + s23;
                Ism[ty + 16 * j][tx + 16 * i] = s + bsh[tx + 16 * i];
            }
        __syncthreads();

        // f32 LIF scan over this chunk; one thread per h.
        if (tid < BN) {
            const size_t srow = ((size_t)(bb * T_ + t0)) * HID_ + h0 + tid;
#pragma unroll 4
            for (int t = 0; t < BM; ++t) {
                const float It = Ism[t][tid];
                const float am = ALPHA_F * mem;   // rounded mul
                mem = am + It;                    // rounded add
                const bool fire = (mem >= 1.0f);
                spikes[srow + (size_t)t * HID_] = fire ? 1.0f : 0.0f;
                if (fire) mem = 0.0f;
            }
        }
        // next chunk's first in-loop barrier orders these Ism reads before
        // the next epilogue's Ism writes (As/Bs staging doesn't touch Ism).
    }

    if (tid < BN) memf[(size_t)bb * HID_ + h0 + tid] = mem;
}

extern "C" void kernel_launch(void* const* d_in, const int* in_sizes, int n_in,
                              void* d_out, int out_size, void* d_ws, size_t ws_size,
                              hipStream_t stream) {
    const float* x    = (const float*)d_in[0];   // [B,T,K] f32
    const float* W    = (const float*)d_in[1];   // [H,K] f32
    const float* bias = (const float*)d_in[2];   // [H] f32
    float* out    = (float*)d_out;
    float* spikes = out;                          // [B,T,H]
    float* memf   = out + (size_t)B_ * T_ * HID_; // [B,H]

    dim3 grid(B_, HID_ / BN);   // 64 x 16 = 1024 blocks
    snn_np_exact<<<grid, dim3(256), 0, stream>>>(x, W, bias, spikes, memf);
}